// Round 2
// baseline (70.948 us; speedup 1.0000x reference)
//
#include <hip/hip_runtime.h>

#define BB 4096
#define TT 80
#define VV 10000
#define EE 100
#define HH 64
#define STRW 68   // u32 row stride for packed state (68 mod 32 = 4 -> 2-way max)

typedef __attribute__((ext_vector_type(8))) short s8v;      // 8 bf16
typedef __attribute__((ext_vector_type(4))) float f4v;      // 4 fp32
typedef __attribute__((ext_vector_type(4))) unsigned u4v;   // 4 u32

#define MFMA(a, b, c) __builtin_amdgcn_mfma_f32_16x16x32_bf16((a), (b), (c), 0, 0, 0)

__device__ __forceinline__ unsigned f2u(float f) { return __float_as_uint(f); }
__device__ __forceinline__ float u2f(unsigned u) { return __uint_as_float(u); }

// tanh(x) = 1 - 2/(exp(2x)+1), clamped so exp2 never overflows
__device__ __forceinline__ float fast_tanh(float x) {
    x = __builtin_amdgcn_fmed3f(x, -10.0f, 10.0f);
    float e = __builtin_amdgcn_exp2f(x * 2.8853900817779268f); // exp(2x)
    return 1.0f - 2.0f * __builtin_amdgcn_rcpf(e + 1.0f);
}

__device__ __forceinline__ s8v mk8(unsigned a, unsigned b, unsigned c, unsigned d) {
    union { unsigned u[4]; s8v s; } t;
    t.u[0] = a; t.u[1] = b; t.u[2] = c; t.u[3] = d;
    return t.s;
}

// Packed state word: P = (bf16_hi << 16) | bf16_residual.
__device__ __forceinline__ s8v pk_hi(u4v a, u4v b) {
    return mk8(__builtin_amdgcn_perm(a[1], a[0], 0x07060302u),
               __builtin_amdgcn_perm(a[3], a[2], 0x07060302u),
               __builtin_amdgcn_perm(b[1], b[0], 0x07060302u),
               __builtin_amdgcn_perm(b[3], b[2], 0x07060302u));
}
__device__ __forceinline__ s8v pk_lo(u4v a, u4v b) {
    return mk8(__builtin_amdgcn_perm(a[1], a[0], 0x05040100u),
               __builtin_amdgcn_perm(a[3], a[2], 0x05040100u),
               __builtin_amdgcn_perm(b[1], b[0], 0x05040100u),
               __builtin_amdgcn_perm(b[3], b[2], 0x05040100u));
}

__device__ __forceinline__ unsigned packsplit(float h) {
    unsigned bits = f2u(h);
    unsigned hi = bits & 0xffff0000u;
    float resid = h - u2f(hi);
    return hi | (f2u(resid) >> 16);
}

// B-fragment (hi/lo) for W[k][c]: frag elem i <- W[32*kf + 8*g + i][c]
__device__ __forceinline__ void load_wfrag(const float* __restrict__ W, int kf, int g,
                                           int c, s8v& hi, s8v& lo) {
    unsigned wb[8], rb[8];
#pragma unroll
    for (int i = 0; i < 8; ++i) {
        float wv = W[(32 * kf + 8 * g + i) * HH + c];
        unsigned bits = f2u(wv);
        float hif = u2f(bits & 0xffff0000u);
        float resid = wv - hif;
        wb[i] = bits;
        rb[i] = f2u(resid);
    }
    hi = mk8((wb[0] >> 16) | (wb[1] & 0xffff0000u),
             (wb[2] >> 16) | (wb[3] & 0xffff0000u),
             (wb[4] >> 16) | (wb[5] & 0xffff0000u),
             (wb[6] >> 16) | (wb[7] & 0xffff0000u));
    lo = mk8((rb[0] >> 16) | (rb[1] & 0xffff0000u),
             (rb[2] >> 16) | (rb[3] & 0xffff0000u),
             (rb[4] >> 16) | (rb[5] & 0xffff0000u),
             (rb[6] >> 16) | (rb[7] & 0xffff0000u));
}

// emb2[v][j] = sum_e emb[v][e] * Wx0[e][j] + b0[j]
__global__ __launch_bounds__(256) void emb2_kernel(const float* __restrict__ emb,
                                                   const float* __restrict__ Wx0,
                                                   const float* __restrict__ b0,
                                                   float* __restrict__ emb2) {
    __shared__ float embL[16 * EE];
    const int v0 = blockIdx.x * 16;
    for (int i = threadIdx.x; i < 16 * EE; i += 256)
        embL[i] = emb[(size_t)v0 * EE + i];
    __syncthreads();
    const int wid = threadIdx.x >> 6;
    const int lane = threadIdx.x & 63;
    const float bb = b0[lane];
    float a0 = bb, a1 = bb, a2 = bb, a3 = bb;
    const float* e0 = &embL[(4 * wid) * EE];
#pragma unroll 4
    for (int e = 0; e < EE; ++e) {
        float w = Wx0[e * HH + lane];
        a0 = fmaf(e0[e], w, a0);
        a1 = fmaf(e0[e + EE], w, a1);
        a2 = fmaf(e0[e + 2 * EE], w, a2);
        a3 = fmaf(e0[e + 3 * EE], w, a3);
    }
    const int r = v0 + 4 * wid;
    emb2[(size_t)(r + 0) * HH + lane] = a0;
    emb2[(size_t)(r + 1) * HH + lane] = a1;
    emb2[(size_t)(r + 2) * HH + lane] = a2;
    emb2[(size_t)(r + 3) * HH + lane] = a3;
}

// K-split wave-pair pipeline: 8 waves (2/SIMD), 16 batch rows.
// Wave pair (tile, tile+4) shares a 16-col output tile; role A (kf=0) handles
// k=0..31 of every dot product, role B (kf=1) handles k=32..63.
// Each phase: both roles compute their K-half partials for BOTH layers
// (9 MFMAs each), exchange one f4v through LDS, then A finishes h0(p) and
// B finishes h1(p-1). Two barriers per phase; critical path per wave is
// half of the merged R1 kernel, with 2 waves/SIMD to hide latency.
__global__ __launch_bounds__(512, 1) void rnn_pipe(
    const int* __restrict__ tokens, const float* __restrict__ emb2,
    const float* __restrict__ Wh0, const float* __restrict__ Wx1,
    const float* __restrict__ Wh1, const float* __restrict__ b1,
    const float* __restrict__ Wout, const float* __restrict__ bout,
    float* __restrict__ out) {
    __shared__ __align__(16) unsigned H0p[2][16][STRW];
    __shared__ __align__(16) unsigned H1p[2][16][STRW];
    __shared__ __align__(16) float XP[4][256];  // L0 partial (from B, for A)
    __shared__ __align__(16) float XQ[4][256];  // L1 partial (from A, for B)
    __shared__ int tokB[16 * TT];               // pre-scaled byte offsets

    const int tid = threadIdx.x;
    const int w8 = tid >> 6;
    const int l = tid & 63;
    const int g = l >> 4;
    const int r16 = l & 15;
    const int tile = w8 & 3;
    const int kf = w8 >> 2;            // 0 = role A, 1 = role B
    const bool isA = (kf == 0);
    const int c = 16 * tile + r16;     // my output column
    const int kb = 32 * kf;            // my K-half base
    const int R = blockIdx.x * 16;

    for (int i = tid; i < 16 * TT; i += 512) tokB[i] = tokens[R * TT + i] << 8;

    s8v wh0h, wh0l, wx1h, wx1l, wh1h, wh1l;   // my K-half weight B-frags
    load_wfrag(Wh0, kf, g, c, wh0h, wh0l);
    load_wfrag(Wx1, kf, g, c, wx1h, wx1l);
    load_wfrag(Wh1, kf, g, c, wh1h, wh1l);
    const float b1j = b1[c];
    const float woj = Wout[l];
    const f4v z4 = {0.f, 0.f, 0.f, 0.f};
    const f4v b1A = isA ? (f4v){b1j, b1j, b1j, b1j} : z4;  // bias only once
    const s8v z8 = mk8(0u, 0u, 0u, 0u);

    // role-selected pointers (wave-uniform, hoisted out of the loop)
    float* expSlot = isA ? &XQ[tile][4 * l] : &XP[tile][4 * l];
    const float* impSlot = isA ? &XP[tile][4 * l] : &XQ[tile][4 * l];
    unsigned* Hmine[2] = {isA ? &H0p[0][0][0] : &H1p[0][0][0],
                          isA ? &H0p[1][0][0] : &H1p[1][0][0]};
    const char* ebase = (const char*)emb2 + 4 * c;

    __syncthreads();   // tokens staged

    s8v a0h = z8, a0l = z8, a1h = z8, a1l = z8;
    f4v xc = z4, xn = z4;

    // ---- phase 0: h0(0) = tanh(x0), role A only ----
    if (isA) {
#pragma unroll
        for (int q = 0; q < 4; ++q)
            xc[q] = *(const float*)(ebase + tokB[(4 * g + q) * TT]);
#pragma unroll
        for (int q = 0; q < 4; ++q)
            xn[q] = *(const float*)(ebase + tokB[(4 * g + q) * TT + 1]);
#pragma unroll
        for (int q = 0; q < 4; ++q)
            H0p[0][4 * g + q][c] = packsplit(fast_tanh(xc[q]));
        xc = xn;
    }
    __syncthreads();
    {   // read h0(0) frags for my K-half; a1 stays zero (h1(-1) = 0)
        const unsigned* bp = &H0p[0][r16][kb + 8 * g];
        u4v t0 = *(const u4v*)bp, t1 = *(const u4v*)(bp + 4);
        a0h = pk_hi(t0, t1);
        a0l = pk_lo(t0, t1);
    }

    // ---- main loop p = 1..TT-1 ----
#pragma unroll 2
    for (int p = 1; p <= TT - 1; ++p) {
        const int par = p & 1;
        if (isA && p <= TT - 2) {
#pragma unroll
            for (int q = 0; q < 4; ++q)
                xn[q] = *(const float*)(ebase + tokB[(4 * g + q) * TT + p + 1]);
        }
        // L1 K-half partial (exported by A, kept by B): 2 parallel 3-chains
        f4v qa = b1A;
        qa = MFMA(a0h, wx1h, qa); qa = MFMA(a0l, wx1h, qa); qa = MFMA(a0h, wx1l, qa);
        f4v qb = z4;
        qb = MFMA(a1h, wh1h, qb); qb = MFMA(a1l, wh1h, qb); qb = MFMA(a1h, wh1l, qb);
        f4v pL1 = qa + qb;
        // L0 K-half partial (kept by A, exported by B); B's xc is zero
        f4v pL0 = xc;
        pL0 = MFMA(a0h, wh0h, pL0); pL0 = MFMA(a0l, wh0h, pL0); pL0 = MFMA(a0h, wh0l, pL0);
        *(f4v*)expSlot = isA ? pL1 : pL0;
        __syncthreads();   // partials visible
        f4v partner = *(const f4v*)impSlot;
        f4v acc = partner + (isA ? pL0 : pL1);
        unsigned* hd = Hmine[par];
#pragma unroll
        for (int q = 0; q < 4; ++q)
            hd[(4 * g + q) * STRW + c] = packsplit(fast_tanh(acc[q]));
        if (isA && p <= TT - 2) xc = xn;
        __syncthreads();   // h0(p), h1(p-1) visible
        // read next-phase A-frags (my K-half of h0(p) and h1(p-1))
        const unsigned* p0 = &H0p[par][r16][kb + 8 * g];
        u4v t0 = *(const u4v*)p0, t1 = *(const u4v*)(p0 + 4);
        const unsigned* p1 = &H1p[par][r16][kb + 8 * g];
        u4v s0 = *(const u4v*)p1, s1 = *(const u4v*)(p1 + 4);
        a0h = pk_hi(t0, t1); a0l = pk_lo(t0, t1);
        a1h = pk_hi(s0, s1); a1l = pk_lo(s0, s1);
    }

    // ---- final phase p = TT (par 0): L1 only -> h1(79) ----
    {
        f4v qa = b1A;
        qa = MFMA(a0h, wx1h, qa); qa = MFMA(a0l, wx1h, qa); qa = MFMA(a0h, wx1l, qa);
        f4v qb = z4;
        qb = MFMA(a1h, wh1h, qb); qb = MFMA(a1l, wh1h, qb); qb = MFMA(a1h, wh1l, qb);
        f4v pL1 = qa + qb;
        *(f4v*)expSlot = pL1;   // A's export matters; B's write is harmless
        __syncthreads();
        if (!isA) {
            f4v qA = *(const f4v*)&XQ[tile][4 * l];
            f4v acc = qA + pL1;
#pragma unroll
            for (int q = 0; q < 4; ++q)
                H1p[0][4 * g + q][c] = packsplit(fast_tanh(acc[q]));
        }
        __syncthreads();
    }

    // Epilogue: out = sigmoid(h1(79) @ Wout + bout). Wave w8 -> rows 2*w8..+1.
#pragma unroll
    for (int q = 0; q < 2; ++q) {
        int row = 2 * w8 + q;
        unsigned P = H1p[0][row][l];
        float v = u2f(P & 0xffff0000u) + u2f(P << 16);
        float pp = v * woj;
#pragma unroll
        for (int off = 32; off > 0; off >>= 1) pp += __shfl_xor(pp, off, 64);
        if (l == 0) {
            float logit = pp + bout[0];
            out[R + row] = __builtin_amdgcn_rcpf(
                1.0f + __builtin_amdgcn_exp2f(-1.4426950408889634f * logit));
        }
    }
}

extern "C" void kernel_launch(void* const* d_in, const int* in_sizes, int n_in,
                              void* d_out, int out_size, void* d_ws, size_t ws_size,
                              hipStream_t stream) {
    const int*   tokens = (const int*)  d_in[0];
    const float* emb    = (const float*)d_in[1];
    const float* Wx0    = (const float*)d_in[2];
    const float* Wh0    = (const float*)d_in[3];
    const float* b0     = (const float*)d_in[4];
    const float* Wx1    = (const float*)d_in[5];
    const float* Wh1    = (const float*)d_in[6];
    const float* b1     = (const float*)d_in[7];
    const float* Wout   = (const float*)d_in[8];
    const float* bout   = (const float*)d_in[9];
    float* out  = (float*)d_out;
    float* emb2 = (float*)d_ws;   // VV*HH floats = 2.56 MB

    emb2_kernel<<<VV / 16, 256, 0, stream>>>(emb, Wx0, b0, emb2);
    rnn_pipe<<<BB / 16, 512, 0, stream>>>(tokens, emb2, Wh0, Wx1, Wh1, b1,
                                          Wout, bout, out);
}